// Round 6
// baseline (641.297 us; speedup 1.0000x reference)
//
#include <hip/hip_runtime.h>
#include <hip/hip_bf16.h>

typedef __hip_bfloat16 bf16;
typedef __attribute__((ext_vector_type(8))) short bf16x8;          // 8 bf16 = 4 VGPRs
typedef __attribute__((ext_vector_type(8))) unsigned short ushort8;
typedef __attribute__((ext_vector_type(4))) float f32x4;

#define N_NODES 50000
#define E_RAW   800000
#define E_TOT   850000      // E_RAW + N self-loops
#define H_HEADS 8
#define F_DIM   256
#define NB_SCAN 196         // ceil(50000/256)

// ---- dtype-agnostic loads: flags[0]=1 -> floats are fp32; flags[1]=1 -> ints are int32
__device__ __forceinline__ float loadF(const void* p, size_t i, int f32) {
    return f32 ? ((const float*)p)[i] : __bfloat162float(((const bf16*)p)[i]);
}
__device__ __forceinline__ int loadI(const void* p, size_t i, int is32) {
    return is32 ? ((const int*)p)[i] : (int)((const long long*)p)[i];
}
__device__ __forceinline__ float bfu(unsigned short u) {
    return __uint_as_float((unsigned)u << 16);
}

// ---- detect input dtypes from data (deterministic; graph-capture safe) ----
__global__ void detect(const void* __restrict__ x, const void* __restrict__ ei,
                       int* __restrict__ flags) {
    int t = threadIdx.x;
    const unsigned short* xs = (const unsigned short*)x;
    int f32 = 0;
    for (int i = t; i < 8192; i += 256) {
        unsigned e = (xs[i] >> 7) & 0xFF;   // bf16 exponent field
        if (e >= 134) f32 = 1;              // impossible for bf16 N(0,1) data
    }
    const int* eii = (const int*)ei;
    int odd = 0;                            // nonzero odd 32-bit slot -> int32 ids
    for (int i = t; i < 1024; i += 256)
        if (eii[2 * i + 1] != 0) odd = 1;
    if (f32) atomicOr(&flags[0], 1);
    if (odd) atomicOr(&flags[1], 1);
}

// ---- convert x -> bf16; weights -> bf16 in MFMA B-fragment ("swizzled") order.
// Swizzle for a [K,512] cat-matrix: element (k,n) -> ((kb*32+ctg)*64+lane)*8+j
// with kb=k>>5, j=k&7, lane=((k>>3)&3)*16+(n&15), ctg=n>>4.
__global__ void convert(const void* __restrict__ x,
                        const void* __restrict__ wl1, const void* __restrict__ wr1,
                        const void* __restrict__ wl2, const void* __restrict__ wr2,
                        bf16* __restrict__ xb, bf16* __restrict__ wb,
                        const int* __restrict__ flags) {
    const int f32 = flags[0];
    const size_t XTOT = (size_t)N_NODES * 128;         // 6.4M
    const size_t TOT  = XTOT + 196608;
    for (size_t i = blockIdx.x * 256 + threadIdx.x; i < TOT; i += (size_t)gridDim.x * 256) {
        if (i < XTOT) {
            xb[i] = __float2bfloat16(loadF(x, i, f32));
        } else {
            size_t j = i - XTOT;
            const void* src; size_t off, base;
            int k, n;
            if (j < 65536) {                           // layer-1 cat [Wl1|Wr1], K=128
                int half = j >= 32768;
                off = j - (size_t)half * 32768;
                src = half ? wr1 : wl1;
                k = (int)(off >> 8); n = half * 256 + (int)(off & 255);
                base = 0;
            } else {                                   // layer-2 cat [Wl2|Wr2], K=256
                size_t jj = j - 65536;
                int half = jj >= 65536;
                off = jj - (size_t)half * 65536;
                src = half ? wr2 : wl2;
                k = (int)(off >> 8); n = half * 256 + (int)(off & 255);
                base = 65536;
            }
            int kb = k >> 5, jo = k & 7;
            int lane = ((k >> 3) & 3) * 16 + (n & 15);
            int ctg = n >> 4;
            size_t dst = base + (((size_t)(kb * 32 + ctg) * 64 + lane) * 8 + jo);
            wb[dst] = __float2bfloat16(loadF(src, off, f32));
        }
    }
}

// ---- CSR build ---------------------------------------------------------------
__global__ void hist(const void* __restrict__ ei, int* __restrict__ counts,
                     const int* __restrict__ flags) {
    const int is32 = flags[1];
    int e = blockIdx.x * 256 + threadIdx.x;
    if (e >= E_TOT) return;
    int d = (e < E_RAW) ? loadI(ei, (size_t)E_RAW + e, is32) : (e - E_RAW);
    atomicAdd(&counts[d], 1);
}

__global__ void scan1(const int* __restrict__ counts, int* __restrict__ rp,
                      int* __restrict__ bsum) {
    __shared__ int sm[256];
    int b = blockIdx.x, t = threadIdx.x;
    int i = b * 256 + t;
    int v = (i < N_NODES) ? counts[i] : 0;
    sm[t] = v; __syncthreads();
    for (int off = 1; off < 256; off <<= 1) {
        int u = (t >= off) ? sm[t - off] : 0;
        __syncthreads();
        sm[t] += u;
        __syncthreads();
    }
    int incl = sm[t];
    if (i < N_NODES) rp[i] = incl - v;      // local exclusive
    if (t == 255) bsum[b] = incl;
}

__global__ void scan2(int* __restrict__ bsum) {
    __shared__ int sm[256];
    int t = threadIdx.x;
    int v = (t < NB_SCAN) ? bsum[t] : 0;
    sm[t] = v; __syncthreads();
    for (int off = 1; off < 256; off <<= 1) {
        int u = (t >= off) ? sm[t - off] : 0;
        __syncthreads();
        sm[t] += u;
        __syncthreads();
    }
    if (t < NB_SCAN) bsum[t] = sm[t] - v;   // exclusive
}

__global__ void scan3(int* __restrict__ rp, const int* __restrict__ bsum,
                      int* __restrict__ cursor) {
    int b = blockIdx.x, t = threadIdx.x;
    int i = b * 256 + t;
    if (i < N_NODES) {
        int r = rp[i] + bsum[b];
        rp[i] = r;
        cursor[i] = r;
    }
    if (i == 0) rp[N_NODES] = E_TOT;
}

__global__ void fill(const void* __restrict__ ei, int* __restrict__ cursor,
                     int* __restrict__ srcs, const int* __restrict__ flags) {
    const int is32 = flags[1];
    int e = blockIdx.x * 256 + threadIdx.x;
    if (e >= E_TOT) return;
    int s, d;
    if (e < E_RAW) { s = loadI(ei, e, is32); d = loadI(ei, (size_t)E_RAW + e, is32); }
    else           { s = d = e - E_RAW; }
    int pos = atomicAdd(&cursor[d], 1);
    srcs[pos] = s;
}

// ---- MFMA dual-GEMM, LDS-free: [Cl|Cr][M,512] = A[M,K] @ Wsw[K,512] ----------
// W pre-swizzled to B-frag order; each wave loads its own frags (1KB coalesced).
__launch_bounds__(256)
__global__ void gemm_mfma(const bf16* __restrict__ A, const bf16* __restrict__ Wsw,
                          bf16* __restrict__ Cl, bf16* __restrict__ Cr,
                          int M, int K) {
    const int tid = threadIdx.x;
    const int w = tid >> 6, lane = tid & 63, q = lane >> 4, l16 = lane & 15;
    const int bRow = blockIdx.x * 64;
    const int ctgBase = blockIdx.y * 16;      // 256 cols per block (16 col-groups)
    int rowA = bRow + w * 16 + l16;
    if (rowA >= M) rowA = M - 1;              // clamp; stores are guarded
    const short* Ap = (const short*)A + (size_t)rowA * K + q * 8;
    const short* Wp = (const short*)Wsw;
    const int nkb = K >> 5;
    f32x4 acc[16] = {};
    for (int kb = 0; kb < nkb; ++kb) {
        bf16x8 af = *(const bf16x8*)(Ap + kb * 32);
        const short* bb = Wp + ((size_t)(kb * 32 + ctgBase) * 64 + lane) * 8;
#pragma unroll
        for (int ct = 0; ct < 16; ++ct) {
            bf16x8 bfr = *(const bf16x8*)(bb + ct * 512);
            acc[ct] = __builtin_amdgcn_mfma_f32_16x16x32_bf16(af, bfr, acc[ct], 0, 0, 0);
        }
    }
    bf16* C = ctgBase ? Cr : Cl;              // y=0 -> cols 0..255 (Wl half)
#pragma unroll
    for (int ct = 0; ct < 16; ++ct) {
        int col = ct * 16 + l16;
#pragma unroll
        for (int r = 0; r < 4; ++r) {
            int row = bRow + w * 16 + q * 4 + r;
            if (row < M) C[(size_t)row * 256 + col] = __float2bfloat16(acc[ct][r]);
        }
    }
}

// ---- fused GATv2 attention + aggregation, one block per dst node -------------
// Two-phase, chunked (32 edges): phase 1 = one thread per (edge,head) computes
// the logit serially (exec-masked to actual degree); phase 2 = weighted
// accumulation gathering 4B/thread straight from global xl (L2-hot, coalesced).
// mode 1: out = ELU(agg + b) bf16 [256/node]; mode 2: out = mean_heads(agg) + b
__launch_bounds__(256)
__global__ void fused_attn(const int* __restrict__ rp, const int* __restrict__ srcs,
                           const bf16* __restrict__ xl, const bf16* __restrict__ xr,
                           const void* __restrict__ att, const void* __restrict__ bias,
                           void* __restrict__ outp, int mode,
                           const int* __restrict__ flags) {
    const int f32 = flags[0];
    __shared__ float att_sw[8 * 34];          // stride 34: conflict-free per-h float2
    __shared__ float xr_sw[8 * 34];
    __shared__ float ews[32 * 8];             // exp(logit) per (edge,head)
    __shared__ int   srcs_s[32];
    __shared__ float dred[256];
    __shared__ float dfin[8];
    __shared__ float red[512];

    const int d = blockIdx.x, tid = threadIdx.x;
    {   // stage att + xr row (f32, swizzled stride-34)
        int h = tid >> 5, j = tid & 31;
        att_sw[h * 34 + j] = loadF(att, tid, f32);
        xr_sw[h * 34 + j]  = bfu(((const unsigned short*)xr)[(size_t)d * 256 + tid]);
    }
    const int start = rp[d], end = rp[d + 1];
    const int ec = tid >> 3, hh = tid & 7;            // phase-1 role
    const float2* xr2 = (const float2*)(xr_sw + hh * 34);
    const float2* at2 = (const float2*)(att_sw + hh * 34);
    const int half = tid >> 7, pp = tid & 127;        // phase-2 role (2 dims/thread)
    const unsigned short* xlu = (const unsigned short*)xl;
    float mden = 0.f;
    float2 nacc = {0.f, 0.f};

    for (int base = start; base < end; base += 32) {
        int rem = end - base; if (rem > 32) rem = 32;
        if (tid < 32) srcs_s[tid] = srcs[base + tid]; // srcs padded by 64 ints
        __syncthreads();
        // ---- phase 1: logits (exec-masked to rem) ----
        if (ec < rem) {
            int s = srcs_s[ec];
            const ushort8* xp = (const ushort8*)(xlu + (size_t)s * 256 + hh * 32);
            ushort8 rr[4] = {xp[0], xp[1], xp[2], xp[3]};
            float p = 0.f;
#pragma unroll
            for (int qq = 0; qq < 4; ++qq) {
#pragma unroll
                for (int j2 = 0; j2 < 4; ++j2) {
                    float  xa = bfu(rr[qq][j2 * 2]);
                    float  xb = bfu(rr[qq][j2 * 2 + 1]);
                    float2 rv = xr2[qq * 4 + j2];
                    float2 av = at2[qq * 4 + j2];
                    float z0 = xa + rv.x; z0 = fmaxf(z0, 0.2f * z0);
                    float z1 = xb + rv.y; z1 = fmaxf(z1, 0.2f * z1);
                    p = fmaf(z0, av.x, p);
                    p = fmaf(z1, av.y, p);
                }
            }
            float e = __expf(p);
            ews[ec * 8 + hh] = e;
            mden += e;
        }
        __syncthreads();
        // ---- phase 2: weighted accumulation, global gather (waves by parity) ----
        for (int e2 = half; e2 < rem; e2 += 2) {
            float wv = ews[e2 * 8 + (pp >> 4)];
            int s = srcs_s[e2];
            unsigned xv = *(const unsigned*)(xlu + (size_t)s * 256 + pp * 2);
            nacc.x = fmaf(wv, bfu((unsigned short)(xv & 0xFFFF)), nacc.x);
            nacc.y = fmaf(wv, bfu((unsigned short)(xv >> 16)),    nacc.y);
        }
        __syncthreads();
    }
    // ---- denominator reduce ----
    dred[tid] = mden;
    __syncthreads();
    if (tid < 8) {
        float sden = 0.f;
#pragma unroll
        for (int i = 0; i < 32; ++i) sden += dred[i * 8 + tid];
        dfin[tid] = sden + 1e-16f;
    }
    red[half * 256 + pp * 2]     = nacc.x;
    red[half * 256 + pp * 2 + 1] = nacc.y;
    __syncthreads();
    float num = red[tid] + red[256 + tid];
    float v = num / dfin[tid >> 5];

    if (mode == 1) {
        v += loadF(bias, tid, f32);
        v = v > 0.f ? v : expm1f(v);
        ((bf16*)outp)[(size_t)d * 256 + tid] = __float2bfloat16(v);
    } else {
        __syncthreads();
        red[tid] = v;
        __syncthreads();
        if (tid < 32) {
            float s = 0.f;
#pragma unroll
            for (int h = 0; h < H_HEADS; ++h) s += red[h * 32 + tid];
            float o = s * 0.125f + loadF(bias, tid, f32);
            if (f32) ((float*)outp)[(size_t)d * 32 + tid] = o;
            else     ((bf16*)outp)[(size_t)d * 32 + tid] = __float2bfloat16(o);
        }
    }
}

extern "C" void kernel_launch(void* const* d_in, const int* in_sizes, int n_in,
                              void* d_out, int out_size, void* d_ws, size_t ws_size,
                              hipStream_t stream) {
    const void* x    = d_in[0];
    const void* ei   = d_in[1];
    const void* Wl1  = d_in[2];
    const void* Wr1  = d_in[3];
    const void* att1 = d_in[4];
    const void* b1   = d_in[5];
    const void* Wl2  = d_in[6];
    const void* Wr2  = d_in[7];
    const void* att2 = d_in[8];
    const void* b2   = d_in[9];

    // ---- workspace layout (256B-aligned regions) ----
    char* p = (char*)d_ws;
    auto take = [&](size_t bytes) { char* r = p; p += (bytes + 255) & ~(size_t)255; return r; };
    int*  flags  = (int*) take(64 * sizeof(int));
    bf16* xb     = (bf16*)take((size_t)N_NODES * 128 * sizeof(bf16));
    bf16* wb     = (bf16*)take(196608 * sizeof(bf16));
    bf16* xl     = (bf16*)take((size_t)N_NODES * F_DIM * sizeof(bf16));
    bf16* xr     = (bf16*)take((size_t)N_NODES * F_DIM * sizeof(bf16));
    bf16* h1     = (bf16*)take((size_t)N_NODES * F_DIM * sizeof(bf16));
    int*  rp     = (int*) take((N_NODES + 1) * sizeof(int));
    int*  cursor = (int*) take(N_NODES * sizeof(int));
    int*  counts = (int*) take(N_NODES * sizeof(int));
    int*  bsum   = (int*) take(256 * sizeof(int));
    int*  srcs   = (int*) take(((size_t)E_TOT + 64) * sizeof(int)); // +pad (chunk over-read)

    bf16* W1sw = wb;            // [128,512] = [Wl1|Wr1], B-frag order
    bf16* W2sw = wb + 65536;    // [256,512] = [Wl2|Wr2], B-frag order

    (void)hipMemsetAsync(flags, 0, 16, stream);
    (void)hipMemsetAsync(counts, 0, N_NODES * sizeof(int), stream);
    detect<<<1, 256, 0, stream>>>(x, ei, flags);

    // ---- CSR over dst (incl. self-loops) ----
    const int EB = (E_TOT + 255) / 256;
    hist <<<EB, 256, 0, stream>>>(ei, counts, flags);
    scan1<<<NB_SCAN, 256, 0, stream>>>(counts, rp, bsum);
    scan2<<<1, 256, 0, stream>>>(bsum);
    scan3<<<NB_SCAN, 256, 0, stream>>>(rp, bsum, cursor);
    fill <<<EB, 256, 0, stream>>>(ei, cursor, srcs, flags);

    // ---- bf16 conversions + W swizzle ----
    convert<<<2048, 256, 0, stream>>>(x, Wl1, Wr1, Wl2, Wr2, xb, wb, flags);

    dim3 ggrd((N_NODES + 63) / 64, 2);

    // ---- Layer 1 ----
    gemm_mfma<<<ggrd, 256, 0, stream>>>(xb, W1sw, xl, xr, N_NODES, 128);
    fused_attn<<<N_NODES, 256, 0, stream>>>(rp, srcs, xl, xr, att1, b1, h1, 1, flags);

    // ---- Layer 2 ----
    gemm_mfma<<<ggrd, 256, 0, stream>>>(h1, W2sw, xl, xr, N_NODES, 256);
    fused_attn<<<N_NODES, 256, 0, stream>>>(rp, srcs, xl, xr, att2, b2, d_out, 2, flags);
}

// Round 7
// 543.338 us; speedup vs baseline: 1.1803x; 1.1803x over previous
//
#include <hip/hip_runtime.h>
#include <hip/hip_bf16.h>

typedef __hip_bfloat16 bf16;
typedef __attribute__((ext_vector_type(8))) short bf16x8;          // 8 bf16 = 4 VGPRs
typedef __attribute__((ext_vector_type(8))) unsigned short ushort8;
typedef __attribute__((ext_vector_type(4))) float f32x4;

#define N_NODES 50000
#define E_RAW   800000
#define E_TOT   850000      // E_RAW + N self-loops
#define H_HEADS 8
#define F_DIM   256
#define NB_SCAN 196         // ceil(50000/256)

// ---- dtype-agnostic loads: flags[0]=1 -> floats are fp32; flags[1]=1 -> ints are int32
__device__ __forceinline__ float loadF(const void* p, size_t i, int f32) {
    return f32 ? ((const float*)p)[i] : __bfloat162float(((const bf16*)p)[i]);
}
__device__ __forceinline__ int loadI(const void* p, size_t i, int is32) {
    return is32 ? ((const int*)p)[i] : (int)((const long long*)p)[i];
}
__device__ __forceinline__ float bfu(unsigned short u) {
    return __uint_as_float((unsigned)u << 16);
}
__device__ __forceinline__ short f2bfs(float f) {   // RNE f32 -> bf16 bits
    unsigned u = __float_as_uint(f);
    return (short)((u + 0x7fff + ((u >> 16) & 1)) >> 16);
}

// ---- detect input dtypes from data (deterministic; graph-capture safe) ----
__global__ void detect(const void* __restrict__ x, const void* __restrict__ ei,
                       int* __restrict__ flags) {
    int t = threadIdx.x;
    const unsigned short* xs = (const unsigned short*)x;
    int f32 = 0;
    for (int i = t; i < 8192; i += 256) {
        unsigned e = (xs[i] >> 7) & 0xFF;   // bf16 exponent field
        if (e >= 134) f32 = 1;              // impossible for bf16 N(0,1) data
    }
    const int* eii = (const int*)ei;
    int odd = 0;                            // nonzero odd 32-bit slot -> int32 ids
    for (int i = t; i < 1024; i += 256)
        if (eii[2 * i + 1] != 0) odd = 1;
    if (f32) atomicOr(&flags[0], 1);
    if (odd) atomicOr(&flags[1], 1);
}

// ---- weights -> bf16 in MFMA B-fragment ("swizzled") order.
// Swizzle for a [K,512] cat-matrix: element (k,n) -> ((kb*32+ctg)*64+lane)*8+j
// with kb=k>>5, j=k&7, lane=((k>>3)&3)*16+(n&15), ctg=n>>4.
__global__ void convertW(const void* __restrict__ wl1, const void* __restrict__ wr1,
                         const void* __restrict__ wl2, const void* __restrict__ wr2,
                         bf16* __restrict__ wb, const int* __restrict__ flags) {
    const int f32 = flags[0];
    for (size_t j = blockIdx.x * 256 + threadIdx.x; j < 196608;
         j += (size_t)gridDim.x * 256) {
        const void* src; size_t off, base;
        int k, n;
        if (j < 65536) {                           // layer-1 cat [Wl1|Wr1], K=128
            int half = j >= 32768;
            off = j - (size_t)half * 32768;
            src = half ? wr1 : wl1;
            k = (int)(off >> 8); n = half * 256 + (int)(off & 255);
            base = 0;
        } else {                                   // layer-2 cat [Wl2|Wr2], K=256
            size_t jj = j - 65536;
            int half = jj >= 65536;
            off = jj - (size_t)half * 65536;
            src = half ? wr2 : wl2;
            k = (int)(off >> 8); n = half * 256 + (int)(off & 255);
            base = 65536;
        }
        int kb = k >> 5, jo = k & 7;
        int lane = ((k >> 3) & 3) * 16 + (n & 15);
        int ctg = n >> 4;
        size_t dst = base + (((size_t)(kb * 32 + ctg) * 64 + lane) * 8 + jo);
        wb[dst] = __float2bfloat16(loadF(src, off, f32));
    }
}

// ---- CSR build ---------------------------------------------------------------
__global__ void hist(const void* __restrict__ ei, int* __restrict__ counts,
                     const int* __restrict__ flags) {
    const int is32 = flags[1];
    int e = blockIdx.x * 256 + threadIdx.x;
    if (e >= E_TOT) return;
    int d = (e < E_RAW) ? loadI(ei, (size_t)E_RAW + e, is32) : (e - E_RAW);
    atomicAdd(&counts[d], 1);
}

__global__ void scan1(const int* __restrict__ counts, int* __restrict__ rp,
                      int* __restrict__ bsum) {
    __shared__ int sm[256];
    int b = blockIdx.x, t = threadIdx.x;
    int i = b * 256 + t;
    int v = (i < N_NODES) ? counts[i] : 0;
    sm[t] = v; __syncthreads();
    for (int off = 1; off < 256; off <<= 1) {
        int u = (t >= off) ? sm[t - off] : 0;
        __syncthreads();
        sm[t] += u;
        __syncthreads();
    }
    int incl = sm[t];
    if (i < N_NODES) rp[i] = incl - v;      // local exclusive
    if (t == 255) bsum[b] = incl;
}

__global__ void scan2(int* __restrict__ bsum) {
    __shared__ int sm[256];
    int t = threadIdx.x;
    int v = (t < NB_SCAN) ? bsum[t] : 0;
    sm[t] = v; __syncthreads();
    for (int off = 1; off < 256; off <<= 1) {
        int u = (t >= off) ? sm[t - off] : 0;
        __syncthreads();
        sm[t] += u;
        __syncthreads();
    }
    if (t < NB_SCAN) bsum[t] = sm[t] - v;   // exclusive
}

__global__ void scan3(int* __restrict__ rp, const int* __restrict__ bsum,
                      int* __restrict__ cursor) {
    int b = blockIdx.x, t = threadIdx.x;
    int i = b * 256 + t;
    if (i < N_NODES) {
        int r = rp[i] + bsum[b];
        rp[i] = r;
        cursor[i] = r;
    }
    if (i == 0) rp[N_NODES] = E_TOT;
}

__global__ void fill(const void* __restrict__ ei, int* __restrict__ cursor,
                     int* __restrict__ srcs, const int* __restrict__ flags) {
    const int is32 = flags[1];
    int e = blockIdx.x * 256 + threadIdx.x;
    if (e >= E_TOT) return;
    int s, d;
    if (e < E_RAW) { s = loadI(ei, e, is32); d = loadI(ei, (size_t)E_RAW + e, is32); }
    else           { s = d = e - E_RAW; }
    int pos = atomicAdd(&cursor[d], 1);
    srcs[pos] = s;
}

// ---- MFMA dual-GEMM, LDS-free: [Cl|Cr][M,512] = A[M,K] @ Wsw[K,512] ----------
// W pre-swizzled to B-frag order; each wave loads its own frags (1KB coalesced).
// aDyn=1: A dtype follows flags[0] (f32 path converts on load); aDyn=0: A is bf16 ws.
__launch_bounds__(256)
__global__ void gemm_mfma(const void* __restrict__ A, const bf16* __restrict__ Wsw,
                          bf16* __restrict__ Cl, bf16* __restrict__ Cr,
                          int M, int K, int aDyn, const int* __restrict__ flags) {
    const int af32 = aDyn ? flags[0] : 0;
    const int tid = threadIdx.x;
    const int w = tid >> 6, lane = tid & 63, q = lane >> 4, l16 = lane & 15;
    const int bRow = blockIdx.x * 64;
    const int ctgBase = blockIdx.y * 16;      // 256 cols per block (16 col-groups)
    int rowA = bRow + w * 16 + l16;
    if (rowA >= M) rowA = M - 1;              // clamp; stores are guarded
    const short* Ap  = (const short*)A + (size_t)rowA * K + q * 8;
    const float* Apf = (const float*)A + (size_t)rowA * K + q * 8;
    const short* Wp = (const short*)Wsw;
    const int nkb = K >> 5;
    f32x4 acc[16] = {};
    for (int kb = 0; kb < nkb; ++kb) {
        bf16x8 af;
        if (!af32) {
            af = *(const bf16x8*)(Ap + kb * 32);
        } else {
            float4 a0 = *(const float4*)(Apf + kb * 32);
            float4 a1 = *(const float4*)(Apf + kb * 32 + 4);
            af[0] = f2bfs(a0.x); af[1] = f2bfs(a0.y);
            af[2] = f2bfs(a0.z); af[3] = f2bfs(a0.w);
            af[4] = f2bfs(a1.x); af[5] = f2bfs(a1.y);
            af[6] = f2bfs(a1.z); af[7] = f2bfs(a1.w);
        }
        const short* bb = Wp + ((size_t)(kb * 32 + ctgBase) * 64 + lane) * 8;
#pragma unroll
        for (int ct = 0; ct < 16; ++ct) {
            bf16x8 bfr = *(const bf16x8*)(bb + ct * 512);
            acc[ct] = __builtin_amdgcn_mfma_f32_16x16x32_bf16(af, bfr, acc[ct], 0, 0, 0);
        }
    }
    bf16* C = ctgBase ? Cr : Cl;              // y=0 -> cols 0..255 (Wl half)
#pragma unroll
    for (int ct = 0; ct < 16; ++ct) {
        int col = ct * 16 + l16;
#pragma unroll
        for (int r = 0; r < 4; ++r) {
            int row = bRow + w * 16 + q * 4 + r;
            if (row < M) C[(size_t)row * 256 + col] = __float2bfloat16(acc[ct][r]);
        }
    }
}

// ---- fused GATv2 attention + aggregation, one block per dst node -------------
// Phase 1: one thread per (edge,head) computes the logit (float4 LDS reads,
// exec-masked to degree). Phase 2: 4 wave-aligned edge groups; src is wave-
// uniform (readfirstlane -> SGPR base), 8B gather/thread, shift/mask unpack.
// mode 1: out = ELU(agg + b) bf16 [256/node]; mode 2: out = mean_heads(agg) + b
__launch_bounds__(256)
__global__ void fused_attn(const int* __restrict__ rp, const int* __restrict__ srcs,
                           const bf16* __restrict__ xl, const bf16* __restrict__ xr,
                           const void* __restrict__ att, const void* __restrict__ bias,
                           void* __restrict__ outp, int mode,
                           const int* __restrict__ flags) {
    const int f32 = flags[0];
    __shared__ float att_sw[8 * 36];          // stride 36: 16B-aligned float4 per head
    __shared__ float xr_sw[8 * 36];
    __shared__ float ews[32 * 8];             // exp(logit) per (edge,head)
    __shared__ int   srcs_s[32];
    __shared__ float dred[256];
    __shared__ float dfin[8];
    __shared__ f32x4 red4[256];               // [wave][lane] partial num rows

    const int d = blockIdx.x, tid = threadIdx.x;
    {   // stage att + xr row (f32, stride-36)
        int h = tid >> 5, j = tid & 31;
        att_sw[h * 36 + j] = loadF(att, tid, f32);
        xr_sw[h * 36 + j]  = bfu(((const unsigned short*)xr)[(size_t)d * 256 + tid]);
    }
    const int start = rp[d], end = rp[d + 1];
    const int ec = tid >> 3, hh = tid & 7;            // phase-1 role
    const float4* xr4 = (const float4*)(xr_sw + hh * 36);
    const float4* at4 = (const float4*)(att_sw + hh * 36);
    const int wid = tid >> 6, lane = tid & 63;        // phase-2 role (4 dims/thread)
    const unsigned short* xlu = (const unsigned short*)xl;
    float mden = 0.f;
    f32x4 nacc = {0.f, 0.f, 0.f, 0.f};

    for (int base = start; base < end; base += 32) {
        int rem = end - base; if (rem > 32) rem = 32;
        if (tid < 32) srcs_s[tid] = srcs[base + tid]; // srcs padded by 64 ints
        __syncthreads();
        // ---- phase 1: logits (exec-masked to rem) ----
        if (ec < rem) {
            int s = srcs_s[ec];
            const ushort8* xp = (const ushort8*)(xlu + (size_t)s * 256 + hh * 32);
            ushort8 rr[4] = {xp[0], xp[1], xp[2], xp[3]};
            float p = 0.f;
#pragma unroll
            for (int qq = 0; qq < 4; ++qq) {
#pragma unroll
                for (int j4 = 0; j4 < 2; ++j4) {
                    float4 rv = xr4[qq * 2 + j4];
                    float4 av = at4[qq * 2 + j4];
                    float z0 = bfu(rr[qq][j4 * 4 + 0]) + rv.x; z0 = fmaxf(z0, 0.2f * z0);
                    float z1 = bfu(rr[qq][j4 * 4 + 1]) + rv.y; z1 = fmaxf(z1, 0.2f * z1);
                    float z2 = bfu(rr[qq][j4 * 4 + 2]) + rv.z; z2 = fmaxf(z2, 0.2f * z2);
                    float z3 = bfu(rr[qq][j4 * 4 + 3]) + rv.w; z3 = fmaxf(z3, 0.2f * z3);
                    p = fmaf(z0, av.x, p);
                    p = fmaf(z1, av.y, p);
                    p = fmaf(z2, av.z, p);
                    p = fmaf(z3, av.w, p);
                }
            }
            float e = __expf(p);
            ews[ec * 8 + hh] = e;
            mden += e;
        }
        __syncthreads();
        // ---- phase 2: weighted accumulation; s is wave-uniform -> SGPR base ----
        for (int e2 = wid; e2 < rem; e2 += 4) {
            int s = __builtin_amdgcn_readfirstlane(srcs_s[e2]);
            float wv = ews[e2 * 8 + (lane >> 3)];
            const unsigned* xq = (const unsigned*)(xlu + (size_t)s * 256 + lane * 4);
            unsigned x0 = xq[0], x1 = xq[1];
            nacc[0] = fmaf(wv, __uint_as_float(x0 << 16),          nacc[0]);
            nacc[1] = fmaf(wv, __uint_as_float(x0 & 0xffff0000u),  nacc[1]);
            nacc[2] = fmaf(wv, __uint_as_float(x1 << 16),          nacc[2]);
            nacc[3] = fmaf(wv, __uint_as_float(x1 & 0xffff0000u),  nacc[3]);
        }
        __syncthreads();
    }
    // ---- reductions: den over (ec) per head; num over 4 waves ----
    dred[tid] = mden;
    red4[wid * 64 + lane] = nacc;
    __syncthreads();
    if (tid < 8) {
        float sden = 0.f;
#pragma unroll
        for (int i = 0; i < 32; ++i) sden += dred[i * 8 + tid];
        dfin[tid] = sden + 1e-16f;
    }
    __syncthreads();
    const float* redf = (const float*)red4;   // flat: [w*256 + dim]
    float num = redf[tid] + redf[256 + tid] + redf[512 + tid] + redf[768 + tid];
    float v = num / dfin[tid >> 5];

    if (mode == 1) {
        v += loadF(bias, tid, f32);
        v = v > 0.f ? v : expm1f(v);
        ((bf16*)outp)[(size_t)d * 256 + tid] = __float2bfloat16(v);
    } else {
        __syncthreads();
        dred[tid] = v;
        __syncthreads();
        if (tid < 32) {
            float s = 0.f;
#pragma unroll
            for (int h = 0; h < H_HEADS; ++h) s += dred[h * 32 + tid];
            float o = s * 0.125f + loadF(bias, tid, f32);
            if (f32) ((float*)outp)[(size_t)d * 32 + tid] = o;
            else     ((bf16*)outp)[(size_t)d * 32 + tid] = __float2bfloat16(o);
        }
    }
}

extern "C" void kernel_launch(void* const* d_in, const int* in_sizes, int n_in,
                              void* d_out, int out_size, void* d_ws, size_t ws_size,
                              hipStream_t stream) {
    const void* x    = d_in[0];
    const void* ei   = d_in[1];
    const void* Wl1  = d_in[2];
    const void* Wr1  = d_in[3];
    const void* att1 = d_in[4];
    const void* b1   = d_in[5];
    const void* Wl2  = d_in[6];
    const void* Wr2  = d_in[7];
    const void* att2 = d_in[8];
    const void* b2   = d_in[9];

    // ---- workspace layout (256B-aligned regions) ----
    char* p = (char*)d_ws;
    auto take = [&](size_t bytes) { char* r = p; p += (bytes + 255) & ~(size_t)255; return r; };
    int*  flags  = (int*) take(64 * sizeof(int));
    bf16* wb     = (bf16*)take(196608 * sizeof(bf16));
    bf16* xl     = (bf16*)take((size_t)N_NODES * F_DIM * sizeof(bf16));
    bf16* xr     = (bf16*)take((size_t)N_NODES * F_DIM * sizeof(bf16));
    bf16* h1     = (bf16*)take((size_t)N_NODES * F_DIM * sizeof(bf16));
    int*  rp     = (int*) take((N_NODES + 1) * sizeof(int));
    int*  cursor = (int*) take(N_NODES * sizeof(int));
    int*  counts = (int*) take(N_NODES * sizeof(int));
    int*  bsum   = (int*) take(256 * sizeof(int));
    int*  srcs   = (int*) take(((size_t)E_TOT + 64) * sizeof(int)); // +pad (chunk over-read)

    bf16* W1sw = wb;            // [128,512] = [Wl1|Wr1], B-frag order
    bf16* W2sw = wb + 65536;    // [256,512] = [Wl2|Wr2], B-frag order

    (void)hipMemsetAsync(flags, 0, 16, stream);
    (void)hipMemsetAsync(counts, 0, N_NODES * sizeof(int), stream);
    detect<<<1, 256, 0, stream>>>(x, ei, flags);

    // ---- weight swizzle (tiny) ----
    convertW<<<96, 256, 0, stream>>>(Wl1, Wr1, Wl2, Wr2, wb, flags);

    // ---- CSR over dst (incl. self-loops) ----
    const int EB = (E_TOT + 255) / 256;
    hist <<<EB, 256, 0, stream>>>(ei, counts, flags);
    scan1<<<NB_SCAN, 256, 0, stream>>>(counts, rp, bsum);
    scan2<<<1, 256, 0, stream>>>(bsum);
    scan3<<<NB_SCAN, 256, 0, stream>>>(rp, bsum, cursor);
    fill <<<EB, 256, 0, stream>>>(ei, cursor, srcs, flags);

    dim3 ggrd((N_NODES + 63) / 64, 2);

    // ---- Layer 1 (A = x directly; dtype per flags) ----
    gemm_mfma<<<ggrd, 256, 0, stream>>>(x, W1sw, xl, xr, N_NODES, 128, 1, flags);
    fused_attn<<<N_NODES, 256, 0, stream>>>(rp, srcs, xl, xr, att1, b1, h1, 1, flags);

    // ---- Layer 2 ----
    gemm_mfma<<<ggrd, 256, 0, stream>>>(h1, W2sw, xl, xr, N_NODES, 256, 0, flags);
    fused_attn<<<N_NODES, 256, 0, stream>>>(rp, srcs, xl, xr, att2, b2, d_out, 2, flags);
}

// Round 8
// 449.230 us; speedup vs baseline: 1.4275x; 1.2095x over previous
//
#include <hip/hip_runtime.h>
#include <hip/hip_bf16.h>

typedef __hip_bfloat16 bf16;
typedef __attribute__((ext_vector_type(8))) short bf16x8;          // 8 bf16 = 4 VGPRs
typedef __attribute__((ext_vector_type(4))) float f32x4;

#define N_NODES 50000
#define E_RAW   800000
#define E_TOT   850000      // E_RAW + N self-loops
#define H_HEADS 8
#define F_DIM   256
#define NB_SCAN 196         // ceil(50000/256)

// ---- dtype-agnostic loads: flags[0]=1 -> floats are fp32; flags[1]=1 -> ints are int32
__device__ __forceinline__ float loadF(const void* p, size_t i, int f32) {
    return f32 ? ((const float*)p)[i] : __bfloat162float(((const bf16*)p)[i]);
}
__device__ __forceinline__ int loadI(const void* p, size_t i, int is32) {
    return is32 ? ((const int*)p)[i] : (int)((const long long*)p)[i];
}
__device__ __forceinline__ float uasf(unsigned u) { return __uint_as_float(u); }
__device__ __forceinline__ unsigned f2bfbits(float f) {   // RNE f32 -> bf16 bits (low 16)
    unsigned u = __float_as_uint(f);
    return (u + 0x7fff + ((u >> 16) & 1)) >> 16;
}

// ---- detect input dtypes from data (deterministic; graph-capture safe) ----
__global__ void detect(const void* __restrict__ x, const void* __restrict__ ei,
                       int* __restrict__ flags) {
    int t = threadIdx.x;
    const unsigned short* xs = (const unsigned short*)x;
    int f32 = 0;
    for (int i = t; i < 8192; i += 256) {
        unsigned e = (xs[i] >> 7) & 0xFF;   // bf16 exponent field
        if (e >= 134) f32 = 1;              // impossible for bf16 N(0,1) data
    }
    const int* eii = (const int*)ei;
    int odd = 0;                            // nonzero odd 32-bit slot -> int32 ids
    for (int i = t; i < 1024; i += 256)
        if (eii[2 * i + 1] != 0) odd = 1;
    if (f32) atomicOr(&flags[0], 1);
    if (odd) atomicOr(&flags[1], 1);
}

// ---- weights -> bf16 in MFMA B-fragment ("swizzled") order.
__global__ void convertW(const void* __restrict__ wl1, const void* __restrict__ wr1,
                         const void* __restrict__ wl2, const void* __restrict__ wr2,
                         bf16* __restrict__ wb, const int* __restrict__ flags) {
    const int f32 = flags[0];
    for (size_t j = blockIdx.x * 256 + threadIdx.x; j < 196608;
         j += (size_t)gridDim.x * 256) {
        const void* src; size_t off, base;
        int k, n;
        if (j < 65536) {                           // layer-1 cat [Wl1|Wr1], K=128
            int half = j >= 32768;
            off = j - (size_t)half * 32768;
            src = half ? wr1 : wl1;
            k = (int)(off >> 8); n = half * 256 + (int)(off & 255);
            base = 0;
        } else {                                   // layer-2 cat [Wl2|Wr2], K=256
            size_t jj = j - 65536;
            int half = jj >= 65536;
            off = jj - (size_t)half * 65536;
            src = half ? wr2 : wl2;
            k = (int)(off >> 8); n = half * 256 + (int)(off & 255);
            base = 65536;
        }
        int kb = k >> 5, jo = k & 7;
        int lane = ((k >> 3) & 3) * 16 + (n & 15);
        int ctg = n >> 4;
        size_t dst = base + (((size_t)(kb * 32 + ctg) * 64 + lane) * 8 + jo);
        wb[dst] = __float2bfloat16(loadF(src, off, f32));
    }
}

// ---- CSR build ---------------------------------------------------------------
__global__ void hist(const void* __restrict__ ei, int* __restrict__ counts,
                     const int* __restrict__ flags) {
    const int is32 = flags[1];
    int e = blockIdx.x * 256 + threadIdx.x;
    if (e >= E_TOT) return;
    int d = (e < E_RAW) ? loadI(ei, (size_t)E_RAW + e, is32) : (e - E_RAW);
    atomicAdd(&counts[d], 1);
}

__global__ void scan1(const int* __restrict__ counts, int* __restrict__ rp,
                      int* __restrict__ bsum) {
    __shared__ int sm[256];
    int b = blockIdx.x, t = threadIdx.x;
    int i = b * 256 + t;
    int v = (i < N_NODES) ? counts[i] : 0;
    sm[t] = v; __syncthreads();
    for (int off = 1; off < 256; off <<= 1) {
        int u = (t >= off) ? sm[t - off] : 0;
        __syncthreads();
        sm[t] += u;
        __syncthreads();
    }
    int incl = sm[t];
    if (i < N_NODES) rp[i] = incl - v;      // local exclusive
    if (t == 255) bsum[b] = incl;
}

__global__ void scan2(int* __restrict__ bsum) {
    __shared__ int sm[256];
    int t = threadIdx.x;
    int v = (t < NB_SCAN) ? bsum[t] : 0;
    sm[t] = v; __syncthreads();
    for (int off = 1; off < 256; off <<= 1) {
        int u = (t >= off) ? sm[t - off] : 0;
        __syncthreads();
        sm[t] += u;
        __syncthreads();
    }
    if (t < NB_SCAN) bsum[t] = sm[t] - v;   // exclusive
}

__global__ void scan3(int* __restrict__ rp, const int* __restrict__ bsum,
                      int* __restrict__ cursor) {
    int b = blockIdx.x, t = threadIdx.x;
    int i = b * 256 + t;
    if (i < N_NODES) {
        int r = rp[i] + bsum[b];
        rp[i] = r;
        cursor[i] = r;
    }
    if (i == 0) rp[N_NODES] = E_TOT;
}

__global__ void fill(const void* __restrict__ ei, int* __restrict__ cursor,
                     int* __restrict__ srcs, const int* __restrict__ flags) {
    const int is32 = flags[1];
    int e = blockIdx.x * 256 + threadIdx.x;
    if (e >= E_TOT) return;
    int s, d;
    if (e < E_RAW) { s = loadI(ei, e, is32); d = loadI(ei, (size_t)E_RAW + e, is32); }
    else           { s = d = e - E_RAW; }
    int pos = atomicAdd(&cursor[d], 1);
    srcs[pos] = s;
}

// ---- MFMA dual-GEMM, LDS-free: [Cl|Cr][M,512] = A[M,K] @ Wsw[K,512] ----------
__device__ __forceinline__ short f2bfs(float f) {
    unsigned u = __float_as_uint(f);
    return (short)((u + 0x7fff + ((u >> 16) & 1)) >> 16);
}
__launch_bounds__(256)
__global__ void gemm_mfma(const void* __restrict__ A, const bf16* __restrict__ Wsw,
                          bf16* __restrict__ Cl, bf16* __restrict__ Cr,
                          int M, int K, int aDyn, const int* __restrict__ flags) {
    const int af32 = aDyn ? flags[0] : 0;
    const int tid = threadIdx.x;
    const int w = tid >> 6, lane = tid & 63, q = lane >> 4, l16 = lane & 15;
    const int bRow = blockIdx.x * 64;
    const int ctgBase = blockIdx.y * 16;      // 256 cols per block (16 col-groups)
    int rowA = bRow + w * 16 + l16;
    if (rowA >= M) rowA = M - 1;              // clamp; stores are guarded
    const short* Ap  = (const short*)A + (size_t)rowA * K + q * 8;
    const float* Apf = (const float*)A + (size_t)rowA * K + q * 8;
    const short* Wp = (const short*)Wsw;
    const int nkb = K >> 5;
    f32x4 acc[16] = {};
    for (int kb = 0; kb < nkb; ++kb) {
        bf16x8 af;
        if (!af32) {
            af = *(const bf16x8*)(Ap + kb * 32);
        } else {
            float4 a0 = *(const float4*)(Apf + kb * 32);
            float4 a1 = *(const float4*)(Apf + kb * 32 + 4);
            af[0] = f2bfs(a0.x); af[1] = f2bfs(a0.y);
            af[2] = f2bfs(a0.z); af[3] = f2bfs(a0.w);
            af[4] = f2bfs(a1.x); af[5] = f2bfs(a1.y);
            af[6] = f2bfs(a1.z); af[7] = f2bfs(a1.w);
        }
        const short* bb = Wp + ((size_t)(kb * 32 + ctgBase) * 64 + lane) * 8;
#pragma unroll
        for (int ct = 0; ct < 16; ++ct) {
            bf16x8 bfr = *(const bf16x8*)(bb + ct * 512);
            acc[ct] = __builtin_amdgcn_mfma_f32_16x16x32_bf16(af, bfr, acc[ct], 0, 0, 0);
        }
    }
    bf16* C = ctgBase ? Cr : Cl;              // y=0 -> cols 0..255 (Wl half)
#pragma unroll
    for (int ct = 0; ct < 16; ++ct) {
        int col = ct * 16 + l16;
#pragma unroll
        for (int r = 0; r < 4; ++r) {
            int row = bRow + w * 16 + q * 4 + r;
            if (row < M) C[(size_t)row * 256 + col] = __float2bfloat16(acc[ct][r]);
        }
    }
}

// ---- fused GATv2 attention + aggregation: ONE WAVE PER DST -------------------
// Lane l owns dims 4l..4l+3 (head h = l>>3). Per edge: one dwordx2 gather,
// 4-dim logit partial, 3 shfl_xor within the 8-lane head group, exp, 4 fma.
// den per lane (head-uniform). No LDS, no __syncthreads.
// mode 1: out = ELU(agg + b) bf16 [256/dst]; mode 2: out = mean_heads(agg) + b
#define EDGE_BODY(qx, qy)                                                     \
    {                                                                         \
        float x0 = uasf(qx << 16), x1 = uasf(qx & 0xffff0000u);               \
        float x2 = uasf(qy << 16), x3 = uasf(qy & 0xffff0000u);               \
        float z0 = x0 + rv0; z0 = fmaxf(z0, 0.2f * z0);                       \
        float z1 = x1 + rv1; z1 = fmaxf(z1, 0.2f * z1);                       \
        float z2 = x2 + rv2; z2 = fmaxf(z2, 0.2f * z2);                       \
        float z3 = x3 + rv3; z3 = fmaxf(z3, 0.2f * z3);                       \
        float p = z0 * a0; p = fmaf(z1, a1, p);                               \
        p = fmaf(z2, a2, p); p = fmaf(z3, a3, p);                             \
        p += __shfl_xor(p, 1); p += __shfl_xor(p, 2); p += __shfl_xor(p, 4);  \
        float wv = __expf(p);                                                 \
        den += wv;                                                            \
        n0 = fmaf(wv, x0, n0); n1 = fmaf(wv, x1, n1);                         \
        n2 = fmaf(wv, x2, n2); n3 = fmaf(wv, x3, n3);                         \
    }
__launch_bounds__(256)
__global__ void fused_attn(const int* __restrict__ rp, const int* __restrict__ srcs,
                           const bf16* __restrict__ xl, const bf16* __restrict__ xr,
                           const void* __restrict__ att, const void* __restrict__ bias,
                           void* __restrict__ outp, int mode,
                           const int* __restrict__ flags) {
    const int f32 = flags[0];
    const int tid = threadIdx.x, wid = tid >> 6, lane = tid & 63;
    const int d = blockIdx.x * 4 + wid;

    // stage xr row + att in registers (4 dims/lane)
    const unsigned short* xru = (const unsigned short*)xr;
    uint2 xv = *(const uint2*)(xru + (size_t)d * 256 + lane * 4);
    float rv0 = uasf(xv.x << 16), rv1 = uasf(xv.x & 0xffff0000u);
    float rv2 = uasf(xv.y << 16), rv3 = uasf(xv.y & 0xffff0000u);
    float a0, a1, a2, a3;
    if (f32) {
        float4 av = *(const float4*)((const float*)att + lane * 4);
        a0 = av.x; a1 = av.y; a2 = av.z; a3 = av.w;
    } else {
        uint2 av = *(const uint2*)((const unsigned short*)att + lane * 4);
        a0 = uasf(av.x << 16); a1 = uasf(av.x & 0xffff0000u);
        a2 = uasf(av.y << 16); a3 = uasf(av.y & 0xffff0000u);
    }

    const int start = rp[d], end = rp[d + 1];
    const unsigned short* xlu = (const unsigned short*)xl;
    float den = 0.f, n0 = 0.f, n1 = 0.f, n2 = 0.f, n3 = 0.f;
    int i = start;
    for (; i + 1 < end; i += 2) {           // 2-way unroll: two gathers in flight
        int s0 = srcs[i], s1 = srcs[i + 1];
        uint2 q0 = *(const uint2*)(xlu + (size_t)s0 * 256 + lane * 4);
        uint2 q1 = *(const uint2*)(xlu + (size_t)s1 * 256 + lane * 4);
        EDGE_BODY(q0.x, q0.y);
        EDGE_BODY(q1.x, q1.y);
    }
    if (i < end) {
        int s0 = srcs[i];
        uint2 q0 = *(const uint2*)(xlu + (size_t)s0 * 256 + lane * 4);
        EDGE_BODY(q0.x, q0.y);
    }
    float rd = 1.f / (den + 1e-16f);
    float v0 = n0 * rd, v1 = n1 * rd, v2 = n2 * rd, v3 = n3 * rd;

    if (mode == 1) {
        v0 += loadF(bias, lane * 4 + 0, f32);
        v1 += loadF(bias, lane * 4 + 1, f32);
        v2 += loadF(bias, lane * 4 + 2, f32);
        v3 += loadF(bias, lane * 4 + 3, f32);
        v0 = v0 > 0.f ? v0 : expm1f(v0);
        v1 = v1 > 0.f ? v1 : expm1f(v1);
        v2 = v2 > 0.f ? v2 : expm1f(v2);
        v3 = v3 > 0.f ? v3 : expm1f(v3);
        uint2 o;
        o.x = f2bfbits(v0) | (f2bfbits(v1) << 16);
        o.y = f2bfbits(v2) | (f2bfbits(v3) << 16);
        *(uint2*)((unsigned short*)outp + (size_t)d * 256 + lane * 4) = o;
    } else {
        // mean over heads: sum across the 8 lanes with equal (lane&7)
        v0 += __shfl_xor(v0, 8);  v1 += __shfl_xor(v1, 8);
        v2 += __shfl_xor(v2, 8);  v3 += __shfl_xor(v3, 8);
        v0 += __shfl_xor(v0, 16); v1 += __shfl_xor(v1, 16);
        v2 += __shfl_xor(v2, 16); v3 += __shfl_xor(v3, 16);
        v0 += __shfl_xor(v0, 32); v1 += __shfl_xor(v1, 32);
        v2 += __shfl_xor(v2, 32); v3 += __shfl_xor(v3, 32);
        if (lane < 8) {
            int j = lane * 4;
            float o0 = v0 * 0.125f + loadF(bias, j + 0, f32);
            float o1 = v1 * 0.125f + loadF(bias, j + 1, f32);
            float o2 = v2 * 0.125f + loadF(bias, j + 2, f32);
            float o3 = v3 * 0.125f + loadF(bias, j + 3, f32);
            if (f32) {
                float4 o = {o0, o1, o2, o3};
                *(float4*)((float*)outp + (size_t)d * 32 + j) = o;
            } else {
                uint2 o;
                o.x = f2bfbits(o0) | (f2bfbits(o1) << 16);
                o.y = f2bfbits(o2) | (f2bfbits(o3) << 16);
                *(uint2*)((unsigned short*)outp + (size_t)d * 32 + j) = o;
            }
        }
    }
}

extern "C" void kernel_launch(void* const* d_in, const int* in_sizes, int n_in,
                              void* d_out, int out_size, void* d_ws, size_t ws_size,
                              hipStream_t stream) {
    const void* x    = d_in[0];
    const void* ei   = d_in[1];
    const void* Wl1  = d_in[2];
    const void* Wr1  = d_in[3];
    const void* att1 = d_in[4];
    const void* b1   = d_in[5];
    const void* Wl2  = d_in[6];
    const void* Wr2  = d_in[7];
    const void* att2 = d_in[8];
    const void* b2   = d_in[9];

    // ---- workspace layout (256B-aligned regions) ----
    char* p = (char*)d_ws;
    auto take = [&](size_t bytes) { char* r = p; p += (bytes + 255) & ~(size_t)255; return r; };
    int*  flags  = (int*) take(64 * sizeof(int));
    bf16* wb     = (bf16*)take(196608 * sizeof(bf16));
    bf16* xl     = (bf16*)take((size_t)N_NODES * F_DIM * sizeof(bf16));
    bf16* xr     = (bf16*)take((size_t)N_NODES * F_DIM * sizeof(bf16));
    bf16* h1     = (bf16*)take((size_t)N_NODES * F_DIM * sizeof(bf16));
    int*  rp     = (int*) take((N_NODES + 1) * sizeof(int));
    int*  cursor = (int*) take(N_NODES * sizeof(int));
    int*  counts = (int*) take(N_NODES * sizeof(int));
    int*  bsum   = (int*) take(256 * sizeof(int));
    int*  srcs   = (int*) take(((size_t)E_TOT + 64) * sizeof(int));

    bf16* W1sw = wb;            // [128,512] = [Wl1|Wr1], B-frag order
    bf16* W2sw = wb + 65536;    // [256,512] = [Wl2|Wr2], B-frag order

    (void)hipMemsetAsync(flags, 0, 16, stream);
    (void)hipMemsetAsync(counts, 0, N_NODES * sizeof(int), stream);
    detect<<<1, 256, 0, stream>>>(x, ei, flags);

    // ---- weight swizzle (tiny) ----
    convertW<<<96, 256, 0, stream>>>(Wl1, Wr1, Wl2, Wr2, wb, flags);

    // ---- CSR over dst (incl. self-loops) ----
    const int EB = (E_TOT + 255) / 256;
    hist <<<EB, 256, 0, stream>>>(ei, counts, flags);
    scan1<<<NB_SCAN, 256, 0, stream>>>(counts, rp, bsum);
    scan2<<<1, 256, 0, stream>>>(bsum);
    scan3<<<NB_SCAN, 256, 0, stream>>>(rp, bsum, cursor);
    fill <<<EB, 256, 0, stream>>>(ei, cursor, srcs, flags);

    dim3 ggrd((N_NODES + 63) / 64, 2);

    // ---- Layer 1 (A = x directly; dtype per flags) ----
    gemm_mfma<<<ggrd, 256, 0, stream>>>(x, W1sw, xl, xr, N_NODES, 128, 1, flags);
    fused_attn<<<N_NODES / 4, 256, 0, stream>>>(rp, srcs, xl, xr, att1, b1, h1, 1, flags);

    // ---- Layer 2 ----
    gemm_mfma<<<ggrd, 256, 0, stream>>>(h1, W2sw, xl, xr, N_NODES, 256, 0, flags);
    fused_attn<<<N_NODES / 4, 256, 0, stream>>>(rp, srcs, xl, xr, att2, b2, d_out, 2, flags);
}

// Round 9
// 448.540 us; speedup vs baseline: 1.4297x; 1.0015x over previous
//
#include <hip/hip_runtime.h>
#include <hip/hip_bf16.h>

typedef __hip_bfloat16 bf16;
typedef __attribute__((ext_vector_type(8))) short bf16x8;          // 8 bf16 = 4 VGPRs
typedef __attribute__((ext_vector_type(4))) float f32x4;

#define N_NODES 50000
#define E_RAW   800000
#define E_TOT   850000      // E_RAW + N self-loops
#define H_HEADS 8
#define F_DIM   256
#define NB_SCAN 196         // ceil(50000/256)

// ---- dtype-agnostic loads: flags[0]=1 -> floats are fp32; flags[1]=1 -> ints are int32
__device__ __forceinline__ float loadF(const void* p, size_t i, int f32) {
    return f32 ? ((const float*)p)[i] : __bfloat162float(((const bf16*)p)[i]);
}
__device__ __forceinline__ int loadI(const void* p, size_t i, int is32) {
    return is32 ? ((const int*)p)[i] : (int)((const long long*)p)[i];
}
__device__ __forceinline__ float uasf(unsigned u) { return __uint_as_float(u); }
__device__ __forceinline__ unsigned f2bfbits(float f) {   // RNE f32 -> bf16 bits (low 16)
    unsigned u = __float_as_uint(f);
    return (u + 0x7fff + ((u >> 16) & 1)) >> 16;
}

// ---- detect input dtypes from data (deterministic; graph-capture safe) ----
__global__ void detect(const void* __restrict__ x, const void* __restrict__ ei,
                       int* __restrict__ flags) {
    int t = threadIdx.x;
    const unsigned short* xs = (const unsigned short*)x;
    int f32 = 0;
    for (int i = t; i < 8192; i += 256) {
        unsigned e = (xs[i] >> 7) & 0xFF;   // bf16 exponent field
        if (e >= 134) f32 = 1;              // impossible for bf16 N(0,1) data
    }
    const int* eii = (const int*)ei;
    int odd = 0;                            // nonzero odd 32-bit slot -> int32 ids
    for (int i = t; i < 1024; i += 256)
        if (eii[2 * i + 1] != 0) odd = 1;
    if (f32) atomicOr(&flags[0], 1);
    if (odd) atomicOr(&flags[1], 1);
}

// ---- weights -> bf16 in MFMA B-fragment ("swizzled") order.
__global__ void convertW(const void* __restrict__ wl1, const void* __restrict__ wr1,
                         const void* __restrict__ wl2, const void* __restrict__ wr2,
                         bf16* __restrict__ wb, const int* __restrict__ flags) {
    const int f32 = flags[0];
    for (size_t j = blockIdx.x * 256 + threadIdx.x; j < 196608;
         j += (size_t)gridDim.x * 256) {
        const void* src; size_t off, base;
        int k, n;
        if (j < 65536) {                           // layer-1 cat [Wl1|Wr1], K=128
            int half = j >= 32768;
            off = j - (size_t)half * 32768;
            src = half ? wr1 : wl1;
            k = (int)(off >> 8); n = half * 256 + (int)(off & 255);
            base = 0;
        } else {                                   // layer-2 cat [Wl2|Wr2], K=256
            size_t jj = j - 65536;
            int half = jj >= 65536;
            off = jj - (size_t)half * 65536;
            src = half ? wr2 : wl2;
            k = (int)(off >> 8); n = half * 256 + (int)(off & 255);
            base = 65536;
        }
        int kb = k >> 5, jo = k & 7;
        int lane = ((k >> 3) & 3) * 16 + (n & 15);
        int ctg = n >> 4;
        size_t dst = base + (((size_t)(kb * 32 + ctg) * 64 + lane) * 8 + jo);
        wb[dst] = __float2bfloat16(loadF(src, off, f32));
    }
}

// ---- CSR build ---------------------------------------------------------------
__global__ void hist(const void* __restrict__ ei, int* __restrict__ counts,
                     const int* __restrict__ flags) {
    const int is32 = flags[1];
    int e = blockIdx.x * 256 + threadIdx.x;
    if (e >= E_TOT) return;
    int d = (e < E_RAW) ? loadI(ei, (size_t)E_RAW + e, is32) : (e - E_RAW);
    atomicAdd(&counts[d], 1);
}

__global__ void scan1(const int* __restrict__ counts, int* __restrict__ rp,
                      int* __restrict__ bsum) {
    __shared__ int sm[256];
    int b = blockIdx.x, t = threadIdx.x;
    int i = b * 256 + t;
    int v = (i < N_NODES) ? counts[i] : 0;
    sm[t] = v; __syncthreads();
    for (int off = 1; off < 256; off <<= 1) {
        int u = (t >= off) ? sm[t - off] : 0;
        __syncthreads();
        sm[t] += u;
        __syncthreads();
    }
    int incl = sm[t];
    if (i < N_NODES) rp[i] = incl - v;      // local exclusive
    if (t == 255) bsum[b] = incl;
}

__global__ void scan2(int* __restrict__ bsum) {
    __shared__ int sm[256];
    int t = threadIdx.x;
    int v = (t < NB_SCAN) ? bsum[t] : 0;
    sm[t] = v; __syncthreads();
    for (int off = 1; off < 256; off <<= 1) {
        int u = (t >= off) ? sm[t - off] : 0;
        __syncthreads();
        sm[t] += u;
        __syncthreads();
    }
    if (t < NB_SCAN) bsum[t] = sm[t] - v;   // exclusive
}

__global__ void scan3(int* __restrict__ rp, const int* __restrict__ bsum,
                      int* __restrict__ cursor) {
    int b = blockIdx.x, t = threadIdx.x;
    int i = b * 256 + t;
    if (i < N_NODES) {
        int r = rp[i] + bsum[b];
        rp[i] = r;
        cursor[i] = r;
    }
    if (i == 0) rp[N_NODES] = E_TOT;
}

__global__ void fill(const void* __restrict__ ei, int* __restrict__ cursor,
                     int* __restrict__ srcs, const int* __restrict__ flags) {
    const int is32 = flags[1];
    int e = blockIdx.x * 256 + threadIdx.x;
    if (e >= E_TOT) return;
    int s, d;
    if (e < E_RAW) { s = loadI(ei, e, is32); d = loadI(ei, (size_t)E_RAW + e, is32); }
    else           { s = d = e - E_RAW; }
    int pos = atomicAdd(&cursor[d], 1);
    srcs[pos] = s;
}

// ---- MFMA dual-GEMM, LDS-free: [Cl|Cr][M,512] = A[M,K] @ Wsw[K,512] ----------
// Operand-swapped: mfma(Wfrag, NodeFrag) -> each lane holds 4 CONSECUTIVE cols
// of one node row per acc block -> packed dwordx2 epilogue (16 stores vs 64).
__device__ __forceinline__ short f2bfs(float f) {
    unsigned u = __float_as_uint(f);
    return (short)((u + 0x7fff + ((u >> 16) & 1)) >> 16);
}
__launch_bounds__(256)
__global__ void gemm_mfma(const void* __restrict__ A, const bf16* __restrict__ Wsw,
                          bf16* __restrict__ Cl, bf16* __restrict__ Cr,
                          int M, int K, int aDyn, const int* __restrict__ flags) {
    const int af32 = aDyn ? flags[0] : 0;
    const int tid = threadIdx.x;
    const int w = tid >> 6, lane = tid & 63, q = lane >> 4, l16 = lane & 15;
    const int bRow = blockIdx.x * 64;
    const int ctgBase = blockIdx.y * 16;      // 256 cols per block (16 col-groups)
    int rowA = bRow + w * 16 + l16;
    if (rowA >= M) rowA = M - 1;              // clamp; stores are guarded
    const short* Ap  = (const short*)A + (size_t)rowA * K + q * 8;
    const float* Apf = (const float*)A + (size_t)rowA * K + q * 8;
    const short* Wp = (const short*)Wsw;
    const int nkb = K >> 5;
    f32x4 acc[16] = {};
    for (int kb = 0; kb < nkb; ++kb) {
        bf16x8 af;
        if (!af32) {
            af = *(const bf16x8*)(Ap + kb * 32);
        } else {
            float4 a0 = *(const float4*)(Apf + kb * 32);
            float4 a1 = *(const float4*)(Apf + kb * 32 + 4);
            af[0] = f2bfs(a0.x); af[1] = f2bfs(a0.y);
            af[2] = f2bfs(a0.z); af[3] = f2bfs(a0.w);
            af[4] = f2bfs(a1.x); af[5] = f2bfs(a1.y);
            af[6] = f2bfs(a1.z); af[7] = f2bfs(a1.w);
        }
        const short* bb = Wp + ((size_t)(kb * 32 + ctgBase) * 64 + lane) * 8;
#pragma unroll
        for (int ct = 0; ct < 16; ++ct) {
            bf16x8 bfr = *(const bf16x8*)(bb + ct * 512);
            // swapped operands: D[wcol][noderow] == C[noderow][wcol]
            acc[ct] = __builtin_amdgcn_mfma_f32_16x16x32_bf16(bfr, af, acc[ct], 0, 0, 0);
        }
    }
    unsigned short* C = (unsigned short*)(ctgBase ? Cr : Cl);
    int cOff = (ctgBase ? ctgBase - 16 : ctgBase) * 16;   // 0 for both halves
    cOff = 0;
    int row = bRow + w * 16 + l16;
    if (row < M) {
#pragma unroll
        for (int ct = 0; ct < 16; ++ct) {
            int col = cOff + ct * 16 + q * 4;
            uint2 o;
            o.x = f2bfbits(acc[ct][0]) | (f2bfbits(acc[ct][1]) << 16);
            o.y = f2bfbits(acc[ct][2]) | (f2bfbits(acc[ct][3]) << 16);
            *(uint2*)(C + (size_t)row * 256 + col) = o;
        }
    }
}

// ---- fused GATv2 attention + aggregation: TWO DSTS PER WAVE ------------------
// Lanes 0-31 own dst A, 32-63 dst B. Lane: sub=lane&31 owns dims sub*8..+7
// (head h = sub>>2). Per step the wave processes one edge of EACH dst:
// one dwordx4 gather, float2-packed elementwise, 2 shfl_xor (4-lane head
// group), one exp. Degree imbalance handled by clamped predication.
#define EDGE2(Q, PRED)                                                        \
    {                                                                         \
        float2 X0 = {uasf(Q.x << 16), uasf(Q.x & 0xffff0000u)};               \
        float2 X1 = {uasf(Q.y << 16), uasf(Q.y & 0xffff0000u)};               \
        float2 X2 = {uasf(Q.z << 16), uasf(Q.z & 0xffff0000u)};               \
        float2 X3 = {uasf(Q.w << 16), uasf(Q.w & 0xffff0000u)};               \
        float2 z0 = {X0.x + rv0.x, X0.y + rv0.y};                             \
        float2 z1 = {X1.x + rv1.x, X1.y + rv1.y};                             \
        float2 z2 = {X2.x + rv2.x, X2.y + rv2.y};                             \
        float2 z3 = {X3.x + rv3.x, X3.y + rv3.y};                             \
        z0.x = fmaxf(z0.x, 0.2f * z0.x); z0.y = fmaxf(z0.y, 0.2f * z0.y);     \
        z1.x = fmaxf(z1.x, 0.2f * z1.x); z1.y = fmaxf(z1.y, 0.2f * z1.y);     \
        z2.x = fmaxf(z2.x, 0.2f * z2.x); z2.y = fmaxf(z2.y, 0.2f * z2.y);     \
        z3.x = fmaxf(z3.x, 0.2f * z3.x); z3.y = fmaxf(z3.y, 0.2f * z3.y);     \
        float2 p2 = {z0.x * a0.x, z0.y * a0.y};                               \
        p2.x = fmaf(z1.x, a1.x, p2.x); p2.y = fmaf(z1.y, a1.y, p2.y);         \
        p2.x = fmaf(z2.x, a2.x, p2.x); p2.y = fmaf(z2.y, a2.y, p2.y);         \
        p2.x = fmaf(z3.x, a3.x, p2.x); p2.y = fmaf(z3.y, a3.y, p2.y);         \
        float p = p2.x + p2.y;                                                \
        p += __shfl_xor(p, 1); p += __shfl_xor(p, 2);                         \
        float wv = (PRED) ? __expf(p) : 0.f;                                  \
        den += wv;                                                            \
        n0.x = fmaf(wv, X0.x, n0.x); n0.y = fmaf(wv, X0.y, n0.y);             \
        n1.x = fmaf(wv, X1.x, n1.x); n1.y = fmaf(wv, X1.y, n1.y);             \
        n2.x = fmaf(wv, X2.x, n2.x); n2.y = fmaf(wv, X2.y, n2.y);             \
        n3.x = fmaf(wv, X3.x, n3.x); n3.y = fmaf(wv, X3.y, n3.y);             \
    }
__launch_bounds__(256)
__global__ void fused_attn(const int* __restrict__ rp, const int* __restrict__ srcs,
                           const bf16* __restrict__ xl, const bf16* __restrict__ xr,
                           const void* __restrict__ att, const void* __restrict__ bias,
                           void* __restrict__ outp, int mode,
                           const int* __restrict__ flags) {
    const int f32 = flags[0];
    const int tid = threadIdx.x, wid = tid >> 6, lane = tid & 63;
    const int sub = lane & 31;
    const int d = blockIdx.x * 8 + wid * 2 + (lane >> 5);

    // xr row: 8 dims/lane at feature offset sub*8
    const unsigned short* xru = (const unsigned short*)xr;
    uint4 xv = *(const uint4*)(xru + (size_t)d * 256 + sub * 8);
    float2 rv0 = {uasf(xv.x << 16), uasf(xv.x & 0xffff0000u)};
    float2 rv1 = {uasf(xv.y << 16), uasf(xv.y & 0xffff0000u)};
    float2 rv2 = {uasf(xv.z << 16), uasf(xv.z & 0xffff0000u)};
    float2 rv3 = {uasf(xv.w << 16), uasf(xv.w & 0xffff0000u)};
    float2 a0, a1, a2, a3;
    if (f32) {
        float4 t0 = *(const float4*)((const float*)att + sub * 8);
        float4 t1 = *(const float4*)((const float*)att + sub * 8 + 4);
        a0 = {t0.x, t0.y}; a1 = {t0.z, t0.w}; a2 = {t1.x, t1.y}; a3 = {t1.z, t1.w};
    } else {
        uint4 av = *(const uint4*)((const unsigned short*)att + sub * 8);
        a0 = {uasf(av.x << 16), uasf(av.x & 0xffff0000u)};
        a1 = {uasf(av.y << 16), uasf(av.y & 0xffff0000u)};
        a2 = {uasf(av.z << 16), uasf(av.z & 0xffff0000u)};
        a3 = {uasf(av.w << 16), uasf(av.w & 0xffff0000u)};
    }

    const int start = rp[d], cnt = rp[d + 1] - start;
    const int cnt1 = cnt - 1;                 // >= 0 (self-loops)
    int mA = __shfl(cnt, 0), mB = __shfl(cnt, 32);
    const int maxc = mA > mB ? mA : mB;
    const int* sp = srcs + start;
    const unsigned short* xlu = (const unsigned short*)xl + sub * 8;

    float den = 0.f;
    float2 n0 = {0,0}, n1 = {0,0}, n2 = {0,0}, n3 = {0,0};
    int i = 0;
    for (; i + 1 < maxc; i += 2) {
        int i0 = i < cnt1 ? i : cnt1;
        int i1 = i + 1 < cnt1 ? i + 1 : cnt1;
        int s0 = sp[i0], s1 = sp[i1];
        uint4 q0 = *(const uint4*)(xlu + (size_t)s0 * 256);
        uint4 q1 = *(const uint4*)(xlu + (size_t)s1 * 256);
        EDGE2(q0, i < cnt);
        EDGE2(q1, i + 1 < cnt);
    }
    if (i < maxc) {
        int i0 = i < cnt1 ? i : cnt1;
        int s0 = sp[i0];
        uint4 q0 = *(const uint4*)(xlu + (size_t)s0 * 256);
        EDGE2(q0, i < cnt);
    }
    float rd = 1.f / (den + 1e-16f);
    float v[8] = {n0.x * rd, n0.y * rd, n1.x * rd, n1.y * rd,
                  n2.x * rd, n2.y * rd, n3.x * rd, n3.y * rd};

    if (mode == 1) {
        float b[8];
        if (f32) {
            float4 t0 = *(const float4*)((const float*)bias + sub * 8);
            float4 t1 = *(const float4*)((const float*)bias + sub * 8 + 4);
            b[0]=t0.x; b[1]=t0.y; b[2]=t0.z; b[3]=t0.w;
            b[4]=t1.x; b[5]=t1.y; b[6]=t1.z; b[7]=t1.w;
        } else {
            uint4 bv = *(const uint4*)((const unsigned short*)bias + sub * 8);
            b[0]=uasf(bv.x<<16); b[1]=uasf(bv.x&0xffff0000u);
            b[2]=uasf(bv.y<<16); b[3]=uasf(bv.y&0xffff0000u);
            b[4]=uasf(bv.z<<16); b[5]=uasf(bv.z&0xffff0000u);
            b[6]=uasf(bv.w<<16); b[7]=uasf(bv.w&0xffff0000u);
        }
        uint4 o;
        unsigned oo[4];
#pragma unroll
        for (int k = 0; k < 4; ++k) {
            float u0 = v[2*k]   + b[2*k];
            float u1 = v[2*k+1] + b[2*k+1];
            u0 = u0 > 0.f ? u0 : expm1f(u0);
            u1 = u1 > 0.f ? u1 : expm1f(u1);
            oo[k] = f2bfbits(u0) | (f2bfbits(u1) << 16);
        }
        o.x = oo[0]; o.y = oo[1]; o.z = oo[2]; o.w = oo[3];
        *(uint4*)((unsigned short*)outp + (size_t)d * 256 + sub * 8) = o;
    } else {
        // mean over heads: reduce across the 8 head-lanes (xor 4,8,16 in-half)
#pragma unroll
        for (int k = 0; k < 8; ++k) {
            v[k] += __shfl_xor(v[k], 4);
            v[k] += __shfl_xor(v[k], 8);
            v[k] += __shfl_xor(v[k], 16);
        }
        if (sub < 4) {
            int j = sub * 8;
            float o[8];
#pragma unroll
            for (int k = 0; k < 8; ++k)
                o[k] = v[k] * 0.125f + loadF(bias, j + k, f32);
            if (f32) {
                float4 o0 = {o[0], o[1], o[2], o[3]};
                float4 o1 = {o[4], o[5], o[6], o[7]};
                *(float4*)((float*)outp + (size_t)d * 32 + j)     = o0;
                *(float4*)((float*)outp + (size_t)d * 32 + j + 4) = o1;
            } else {
                uint4 ob;
                ob.x = f2bfbits(o[0]) | (f2bfbits(o[1]) << 16);
                ob.y = f2bfbits(o[2]) | (f2bfbits(o[3]) << 16);
                ob.z = f2bfbits(o[4]) | (f2bfbits(o[5]) << 16);
                ob.w = f2bfbits(o[6]) | (f2bfbits(o[7]) << 16);
                *(uint4*)((unsigned short*)outp + (size_t)d * 32 + j) = ob;
            }
        }
    }
}

extern "C" void kernel_launch(void* const* d_in, const int* in_sizes, int n_in,
                              void* d_out, int out_size, void* d_ws, size_t ws_size,
                              hipStream_t stream) {
    const void* x    = d_in[0];
    const void* ei   = d_in[1];
    const void* Wl1  = d_in[2];
    const void* Wr1  = d_in[3];
    const void* att1 = d_in[4];
    const void* b1   = d_in[5];
    const void* Wl2  = d_in[6];
    const void* Wr2  = d_in[7];
    const void* att2 = d_in[8];
    const void* b2   = d_in[9];

    // ---- workspace layout (256B-aligned regions) ----
    char* p = (char*)d_ws;
    auto take = [&](size_t bytes) { char* r = p; p += (bytes + 255) & ~(size_t)255; return r; };
    int*  flags  = (int*) take(64 * sizeof(int));
    bf16* wb     = (bf16*)take(196608 * sizeof(bf16));
    bf16* xl     = (bf16*)take((size_t)N_NODES * F_DIM * sizeof(bf16));
    bf16* xr     = (bf16*)take((size_t)N_NODES * F_DIM * sizeof(bf16));
    bf16* h1     = (bf16*)take((size_t)N_NODES * F_DIM * sizeof(bf16));
    int*  rp     = (int*) take((N_NODES + 1) * sizeof(int));
    int*  cursor = (int*) take(N_NODES * sizeof(int));
    int*  counts = (int*) take(N_NODES * sizeof(int));
    int*  bsum   = (int*) take(256 * sizeof(int));
    int*  srcs   = (int*) take(((size_t)E_TOT + 64) * sizeof(int));

    bf16* W1sw = wb;            // [128,512] = [Wl1|Wr1], B-frag order
    bf16* W2sw = wb + 65536;    // [256,512] = [Wl2|Wr2], B-frag order

    (void)hipMemsetAsync(flags, 0, 16, stream);
    (void)hipMemsetAsync(counts, 0, N_NODES * sizeof(int), stream);
    detect<<<1, 256, 0, stream>>>(x, ei, flags);

    // ---- weight swizzle (tiny) ----
    convertW<<<96, 256, 0, stream>>>(Wl1, Wr1, Wl2, Wr2, wb, flags);

    // ---- CSR over dst (incl. self-loops) ----
    const int EB = (E_TOT + 255) / 256;
    hist <<<EB, 256, 0, stream>>>(ei, counts, flags);
    scan1<<<NB_SCAN, 256, 0, stream>>>(counts, rp, bsum);
    scan2<<<1, 256, 0, stream>>>(bsum);
    scan3<<<NB_SCAN, 256, 0, stream>>>(rp, bsum, cursor);
    fill <<<EB, 256, 0, stream>>>(ei, cursor, srcs, flags);

    dim3 ggrd((N_NODES + 63) / 64, 2);

    // ---- Layer 1 (A = x directly; dtype per flags) ----
    gemm_mfma<<<ggrd, 256, 0, stream>>>(x, W1sw, xl, xr, N_NODES, 128, 1, flags);
    fused_attn<<<N_NODES / 8, 256, 0, stream>>>(rp, srcs, xl, xr, att1, b1, h1, 1, flags);

    // ---- Layer 2 ----
    gemm_mfma<<<ggrd, 256, 0, stream>>>(h1, W2sw, xl, xr, N_NODES, 256, 0, flags);
    fused_attn<<<N_NODES / 8, 256, 0, stream>>>(rp, srcs, xl, xr, att2, b2, d_out, 2, flags);
}